// Round 1
// baseline (181.199 us; speedup 1.0000x reference)
//
#include <hip/hip_runtime.h>

// UnbalancedOT Sinkhorn, B=4 H=128 W=512 C=64, EPS=1, TAU=0.95, 10 iters.
// One block per (b,h) problem; full 512x64 C tile staged in LDS (pad +1 -> 65
// stride: f-phase 2-way bank alias (free), g-phase conflict-free).
// All logsumexp single-pass (args bounded, no max-subtraction needed).

#define WD_ 512
#define CC_ 64
#define NITER_ 10

__global__ __launch_bounds__(512, 1)
void uot_sinkhorn_kernel(const float* __restrict__ C, float* __restrict__ out) {
    constexpr int LP = 65;                    // padded LDS row stride
    constexpr float TAU   = 0.95f;
    constexpr float KAPPA = 0.025f;           // (1-TAU)/2
    constexpr float XI    = 0.05f / 1.95f;    // (1-TAU)/(1+TAU)
    constexpr float RHO   = 19.0f;            // EPS*TAU/(1-TAU)
    constexpr float INV_RHO = 1.0f / 19.0f;
    const float log_a = -6.2383246250395075f; // -log(512)
    const float log_b = -4.1588830833596715f; // -log(64)

    __shared__ float Cs[WD_ * LP];   // 130 KiB
    __shared__ float fs[WD_];
    __shared__ float gs[CC_];
    __shared__ float ps[8 * CC_];    // per-wave partial sums for g-phase
    __shared__ float red[8];
    __shared__ float bcast[2];

    const int tid  = threadIdx.x;
    const int lane = tid & 63;
    const int wv   = tid >> 6;

    const size_t base = (size_t)blockIdx.x * (WD_ * CC_);
    const float4* Cg4  = reinterpret_cast<const float4*>(C + base);
    float4*       outg4 = reinterpret_cast<float4*>(out + base);

    // ---- stage C into LDS (coalesced float4 global loads, padded LDS writes) ----
    #pragma unroll
    for (int i = 0; i < 16; ++i) {
        int fi = i * 512 + tid;               // float4 index within problem
        float4 v = Cg4[fi];
        int w  = fi >> 4;
        int c0 = (fi & 15) << 2;
        float* dst = &Cs[w * LP + c0];
        dst[0] = v.x; dst[1] = v.y; dst[2] = v.z; dst[3] = v.w;
    }
    __syncthreads();

    // ---- init f: f[w] = -(log_b + lse_c(-C[w,:])) ; sminF = smin(f, log_a) ----
    float sminF;
    {
        const float* row = &Cs[tid * LP];
        float s0 = 0.f, s1 = 0.f, s2 = 0.f, s3 = 0.f;
        #pragma unroll
        for (int c = 0; c < CC_; c += 4) {
            s0 += __expf(-row[c + 0]);
            s1 += __expf(-row[c + 1]);
            s2 += __expf(-row[c + 2]);
            s3 += __expf(-row[c + 3]);
        }
        float f0 = -(log_b + __logf((s0 + s1) + (s2 + s3)));
        fs[tid] = f0;

        float x = __expf(-f0 * INV_RHO);
        #pragma unroll
        for (int off = 32; off > 0; off >>= 1) x += __shfl_xor(x, off, 64);
        if (lane == 0) red[wv] = x;
        __syncthreads();
        if (tid == 0)
            bcast[0] = ((red[0] + red[1]) + (red[2] + red[3]))
                     + ((red[4] + red[5]) + (red[6] + red[7]));
        __syncthreads();
        sminF = -RHO * (log_a + __logf(bcast[0]));
    }

    for (int it = 0; it < NITER_; ++it) {
        // ---- g update: appg[c] = log sum_w exp(f[w] - C[w,c]) ----
        {
            const int w0 = wv * 64;           // each wave owns 64 rows, lane = column
            float s0 = 0.f, s1 = 0.f, s2 = 0.f, s3 = 0.f;
            #pragma unroll
            for (int j = 0; j < 64; j += 4) {
                s0 += __expf(fs[w0 + j + 0] - Cs[(w0 + j + 0) * LP + lane]);
                s1 += __expf(fs[w0 + j + 1] - Cs[(w0 + j + 1) * LP + lane]);
                s2 += __expf(fs[w0 + j + 2] - Cs[(w0 + j + 2) * LP + lane]);
                s3 += __expf(fs[w0 + j + 3] - Cs[(w0 + j + 3) * LP + lane]);
            }
            ps[wv * 64 + lane] = (s0 + s1) + (s2 + s3);
        }
        __syncthreads();
        if (wv == 0) {                        // wave 0: combine, finish g, wave-lse for sminG2
            float S = 0.f;
            #pragma unroll
            for (int k = 0; k < 8; ++k) S += ps[k * 64 + lane];
            float appg = __logf(S);
            float ng2  = TAU * (log_b - appg) - KAPPA * sminF;
            float t = __expf(-ng2 * INV_RHO);
            #pragma unroll
            for (int off = 32; off > 0; off >>= 1) t += __shfl_xor(t, off, 64);
            float sminG2 = -RHO * (log_b + __logf(t));
            gs[lane] = ng2 + XI * sminG2;
            if (lane == 0) bcast[1] = (1.0f + XI) * sminG2;  // smin(new_g) shift identity
        }
        __syncthreads();
        const float sminG = bcast[1];

        // ---- f update: appf[w] = log sum_c exp(g[c] - C[w,c]) ----
        const float* row = &Cs[tid * LP];
        float s0 = 0.f, s1 = 0.f, s2 = 0.f, s3 = 0.f;
        #pragma unroll
        for (int c = 0; c < CC_; c += 4) {
            s0 += __expf(gs[c + 0] - row[c + 0]);
            s1 += __expf(gs[c + 1] - row[c + 1]);
            s2 += __expf(gs[c + 2] - row[c + 2]);
            s3 += __expf(gs[c + 3] - row[c + 3]);
        }
        float appf = __logf((s0 + s1) + (s2 + s3));
        float nf2  = TAU * (log_a - appf) - KAPPA * sminG;

        float x = __expf(-nf2 * INV_RHO);
        #pragma unroll
        for (int off = 32; off > 0; off >>= 1) x += __shfl_xor(x, off, 64);
        if (lane == 0) red[wv] = x;
        __syncthreads();
        if (tid == 0)
            bcast[0] = ((red[0] + red[1]) + (red[2] + red[3]))
                     + ((red[4] + red[5]) + (red[6] + red[7]));
        __syncthreads();
        float sminF2 = -RHO * (log_a + __logf(bcast[0]));
        fs[tid] = nf2 + XI * sminF2;          // safe: old fs last read before barrier #1
        sminF = (1.0f + XI) * sminF2;         // smin(new_f) shift identity
        __syncthreads();
    }

    // ---- output: exp(f[w] + g[c] - C[w,c]), coalesced float4 stores ----
    #pragma unroll
    for (int i = 0; i < 16; ++i) {
        int fi = i * 512 + tid;
        int w  = fi >> 4;
        int c0 = (fi & 15) << 2;
        const float* src = &Cs[w * LP + c0];
        float fw = fs[w];
        float4 v;
        v.x = __expf(fw + gs[c0 + 0] - src[0]);
        v.y = __expf(fw + gs[c0 + 1] - src[1]);
        v.z = __expf(fw + gs[c0 + 2] - src[2]);
        v.w = __expf(fw + gs[c0 + 3] - src[3]);
        outg4[fi] = v;
    }
}

extern "C" void kernel_launch(void* const* d_in, const int* in_sizes, int n_in,
                              void* d_out, int out_size, void* d_ws, size_t ws_size,
                              hipStream_t stream) {
    const float* C = (const float*)d_in[0];
    float* out = (float*)d_out;
    uot_sinkhorn_kernel<<<dim3(512), dim3(512), 0, stream>>>(C, out);
}

// Round 2
// 153.385 us; speedup vs baseline: 1.1813x; 1.1813x over previous
//
#include <hip/hip_runtime.h>

// UnbalancedOT Sinkhorn, B=4 H=128 W=512 C=64, EPS=1, TAU=0.95, 10 iters.
// Restructured: E = exp(-C) precomputed once in LDS (+ per-thread register row),
// iteration loop is pure FMA matvecs in u=exp(f), v=exp(g) space:
//   appg[c] = log(sum_w u[w] E[w,c]) ; appf[w] = log(sum_c v[c] E[w,c])
//   out[w,c] = u[w] * v[c] * E[w,c]
// smin shift identity carries smin(new) across iters with no recompute.

#define WD_ 512
#define CC_ 64
#define NITER_ 10
#define LP 68   // padded LDS row stride (words): 272 B = 17*16 -> b128-aligned rows,
                // 68 mod 32 = 4 -> bank rotation by 4/row, balanced b128 access

__global__ __launch_bounds__(512, 1)
void uot_sinkhorn_kernel(const float* __restrict__ C, float* __restrict__ out) {
    constexpr float TAU   = 0.95f;
    constexpr float KAPPA = 0.025f;           // (1-TAU)/2
    constexpr float XI    = 0.05f / 1.95f;    // (1-TAU)/(1+TAU)
    constexpr float RHO   = 19.0f;            // EPS*TAU/(1-TAU)
    constexpr float INV_RHO = 1.0f / 19.0f;
    const float log_a = -6.2383246250395075f; // -log(512)
    const float log_b = -4.1588830833596715f; // -log(64)

    __shared__ __align__(16) float Es[WD_ * LP];   // 136 KiB: E = exp(-C)
    __shared__ __align__(16) float us[WD_];        // u = exp(f)
    __shared__ __align__(16) float vs[CC_];        // v = exp(g)
    __shared__ __align__(16) float ps[8 * CC_];    // per-wave g partial col sums
    __shared__ __align__(16) float red[8];

    const int tid  = threadIdx.x;
    const int lane = tid & 63;
    const int wv   = tid >> 6;

    const size_t base = (size_t)blockIdx.x * (WD_ * CC_);
    const float4* Cg4   = reinterpret_cast<const float4*>(C + base);
    float4*       outg4 = reinterpret_cast<float4*>(out + base);

    // ---- stage: coalesced float4 loads of C, store E=exp(-C) to LDS ----
    #pragma unroll
    for (int i = 0; i < 16; ++i) {
        int fi = i * 512 + tid;               // float4 index within problem
        float4 v = Cg4[fi];
        int w  = fi >> 4;
        int c0 = (fi & 15) << 2;
        float4 e;
        e.x = __expf(-v.x); e.y = __expf(-v.y);
        e.z = __expf(-v.z); e.w = __expf(-v.w);
        *reinterpret_cast<float4*>(&Es[w * LP + c0]) = e;
    }
    __syncthreads();

    // ---- per-thread register copy of own row (f-phase reads no LDS) ----
    float4 ER[16];
    #pragma unroll
    for (int k = 0; k < 16; ++k)
        ER[k] = *reinterpret_cast<const float4*>(&Es[tid * LP + 4 * k]);

    // ---- init f: f = -(log_b + log sum_c E[row,:]) ; sminF = smin(f,log_a) ----
    float sminF;
    {
        float s0 = 0.f, s1 = 0.f, s2 = 0.f, s3 = 0.f;
        #pragma unroll
        for (int k = 0; k < 16; ++k) {
            s0 += ER[k].x; s1 += ER[k].y; s2 += ER[k].z; s3 += ER[k].w;
        }
        float fv = -(log_b + __logf((s0 + s1) + (s2 + s3)));
        us[tid] = __expf(fv);

        float x = __expf(-fv * INV_RHO);
        #pragma unroll
        for (int off = 32; off > 0; off >>= 1) x += __shfl_xor(x, off, 64);
        if (lane == 0) red[wv] = x;
        __syncthreads();
        float R = ((red[0] + red[1]) + (red[2] + red[3]))
                + ((red[4] + red[5]) + (red[6] + red[7]));
        sminF = -RHO * (log_a + __logf(R));
    }
    __syncthreads();   // us visible to all before first g-phase

    const int r  = lane >> 4;       // 0..3  (row within 4-row group)
    const int cg = lane & 15;       // 0..15 (column group of 4)
    const int w0 = wv * 64;

    for (int it = 0; it < NITER_; ++it) {
        // ---- g partials: wave wv sums its 64 rows; lane owns 4 cols / 4-row subset ----
        {
            float4 acc; acc.x = 0.f; acc.y = 0.f; acc.z = 0.f; acc.w = 0.f;
            #pragma unroll
            for (int j = 0; j < 16; ++j) {
                int w = w0 + 4 * j + r;
                float uw = us[w];
                float4 e = *reinterpret_cast<const float4*>(&Es[w * LP + 4 * cg]);
                acc.x += uw * e.x; acc.y += uw * e.y;
                acc.z += uw * e.z; acc.w += uw * e.w;
            }
            // reduce over the 4 r-subsets (lanes differing in bits 4,5)
            acc.x += __shfl_xor(acc.x, 16, 64); acc.y += __shfl_xor(acc.y, 16, 64);
            acc.z += __shfl_xor(acc.z, 16, 64); acc.w += __shfl_xor(acc.w, 16, 64);
            acc.x += __shfl_xor(acc.x, 32, 64); acc.y += __shfl_xor(acc.y, 32, 64);
            acc.z += __shfl_xor(acc.z, 32, 64); acc.w += __shfl_xor(acc.w, 32, 64);
            if (lane < 16)
                *reinterpret_cast<float4*>(&ps[wv * 64 + 4 * cg]) = acc;
        }
        __syncthreads();   // (A)

        // ---- g finish (wave 0): combine waves, update g, smin via shift identity ----
        if (wv == 0) {
            float S = 0.f;
            #pragma unroll
            for (int k = 0; k < 8; ++k) S += ps[k * 64 + lane];
            float appg = __logf(S);
            float ng2  = TAU * (log_b - appg) - KAPPA * sminF;
            float t = __expf(-ng2 * INV_RHO);
            #pragma unroll
            for (int off = 32; off > 0; off >>= 1) t += __shfl_xor(t, off, 64);
            float sminG2 = -RHO * (log_b + __logf(t));
            vs[lane] = __expf(ng2 + XI * sminG2);
            if (lane == 0) red[0] = (1.0f + XI) * sminG2;  // stash sminG
        }
        __syncthreads();   // (B)
        const float sminG = red[0];

        // ---- f update: appf = log sum_c v[c]*ER[c]  (registers + uniform v reads) ----
        float s0 = 0.f, s1 = 0.f, s2 = 0.f, s3 = 0.f;
        #pragma unroll
        for (int k = 0; k < 16; ++k) {
            float4 v4 = *reinterpret_cast<const float4*>(&vs[4 * k]);
            s0 += v4.x * ER[k].x; s1 += v4.y * ER[k].y;
            s2 += v4.z * ER[k].z; s3 += v4.w * ER[k].w;
        }
        float appf = __logf((s0 + s1) + (s2 + s3));
        float nf2  = TAU * (log_a - appf) - KAPPA * sminG;

        float x = __expf(-nf2 * INV_RHO);
        #pragma unroll
        for (int off = 32; off > 0; off >>= 1) x += __shfl_xor(x, off, 64);
        if (lane == 0) red[wv] = x;
        __syncthreads();   // (D)
        float R = ((red[0] + red[1]) + (red[2] + red[3]))
                + ((red[4] + red[5]) + (red[6] + red[7]));
        float sminF2 = -RHO * (log_a + __logf(R));
        us[tid] = __expf(nf2 + XI * sminF2);
        sminF = (1.0f + XI) * sminF2;      // smin(new_f) via shift identity
        __syncthreads();   // (C) us visible before next g-phase / output
    }

    // ---- output: out = u[w] * v[c] * E[w,c], coalesced float4 stores ----
    #pragma unroll
    for (int i = 0; i < 16; ++i) {
        int fi = i * 512 + tid;
        int w  = fi >> 4;
        int c0 = (fi & 15) << 2;
        float uw = us[w];
        float4 vv = *reinterpret_cast<const float4*>(&vs[c0]);
        float4 e  = *reinterpret_cast<const float4*>(&Es[w * LP + c0]);
        float4 o;
        o.x = uw * vv.x * e.x; o.y = uw * vv.y * e.y;
        o.z = uw * vv.z * e.z; o.w = uw * vv.w * e.w;
        outg4[fi] = o;
    }
}

extern "C" void kernel_launch(void* const* d_in, const int* in_sizes, int n_in,
                              void* d_out, int out_size, void* d_ws, size_t ws_size,
                              hipStream_t stream) {
    const float* C = (const float*)d_in[0];
    float* out = (float*)d_out;
    uot_sinkhorn_kernel<<<dim3(512), dim3(512), 0, stream>>>(C, out);
}